// Round 3
// baseline (557.783 us; speedup 1.0000x reference)
//
#include <hip/hip_runtime.h>

#define N_TOT 65536
#define C_DIM 128
#define K_CB  1024
#define BN 64
#define BT 64
#define NTILE (K_CB / BT)
#define NROW_B 4
#define NBLK_B (N_TOT / NROW_B)

typedef __attribute__((ext_vector_type(8))) short bf16x8;   // 8 bf16 = 4 VGPR
typedef __attribute__((ext_vector_type(4))) float f32x4;

__device__ __forceinline__ ushort f2bf_rne(float f) {
  unsigned u = __float_as_uint(f);
  return (ushort)((u + 0x7FFFu + ((u >> 16) & 1u)) >> 16);
}

// med3u(a,b,c) = median — inserting pk into sorted (t0<=t1<=t2) yields
// {min(t0,pk), med3(t0,t1,pk), med3(t1,t2,pk)} : 3 VALU vs 5-op min/max chain.
__device__ __forceinline__ unsigned med3u(unsigned a, unsigned b, unsigned c) {
  unsigned d;
  asm("v_med3_u32 %0, %1, %2, %3" : "=v"(d) : "v"(a), "v"(b), "v"(c));
  return d;
}

#define GLDS16(src, dst)                                                       \
  __builtin_amdgcn_global_load_lds(                                            \
      (const __attribute__((address_space(1))) void*)(src),                    \
      (__attribute__((address_space(3))) void*)(dst), 16, 0, 0)

// ---------------------------------------------------------------------------
// prep = cbsq (fp64 row sumsq, frozen math) + cbconv (bf16 RNE, same layout)
// fused; block 0 also zeroes the loss accumulator + done-counter each replay.
// ---------------------------------------------------------------------------
__global__ __launch_bounds__(256) void prep_kernel(
    const float* __restrict__ cb, float* __restrict__ cbsq,
    ushort* __restrict__ cbh, double* __restrict__ acc,
    unsigned* __restrict__ cnt) {
  int w = threadIdx.x >> 6, lane = threadIdx.x & 63;
  int r = blockIdx.x * 4 + w;
  float2 v = reinterpret_cast<const float2*>(cb + (size_t)r * C_DIM)[lane];
  ushort2 h;
  h.x = f2bf_rne(v.x); h.y = f2bf_rne(v.y);
  reinterpret_cast<ushort2*>(cbh + (size_t)r * C_DIM)[lane] = h;
  double s = (double)v.x * (double)v.x + (double)v.y * (double)v.y;
#pragma unroll
  for (int off = 32; off >= 1; off >>= 1) s += __shfl_xor(s, off, 64);
  if (lane == 0) cbsq[r] = (float)s;
  if (blockIdx.x == 0 && threadIdx.x == 0) { *acc = 0.0; *cnt = 0u; }
}

// ---------------------------------------------------------------------------
// MFMA filter, R3: occupancy + sort-VALU.
//  - LDS 53248 -> 36864 (4 blocks/CU): zhS aliases B1 (z dead after A-frag
//    hoist; extra barrier before first B1 prefetch). R2 showed the per-tile
//    latency chain (~1000 cyc) nearly un-overlapped at ~1.2 resident blocks.
//  - Sort: pk = v_and_or_b32(bits,mask,code); top-3 insert = min + 2x med3u
//    (8 -> 5 VALU/key; sort was the longest serial segment of the chain).
//  - Staging/swizzle/pool/rescue layout unchanged from R2 (verified).
// ---------------------------------------------------------------------------
__global__ __launch_bounds__(256, 4) void dist_mfma_kernel(
    const float* __restrict__ ze, const ushort* __restrict__ cbh,
    const float* __restrict__ cbsq, ushort* __restrict__ cand) {
  // [B0 16K | B1 16K (zh aliases) | cbsq 4K]; pool[24832] aliases B0+B1 head.
  __shared__ __align__(16) char smem[36864];
  char* const B0 = smem;
  char* const B1 = smem + 16384;
  ushort* zhS = reinterpret_cast<ushort*>(B1);            // [64][128] xor-swz
  unsigned* pool = reinterpret_cast<unsigned*>(smem);     // [64][97]
  float* const cbsqS = reinterpret_cast<float*>(smem + 32768);

  const int tid = threadIdx.x;
  const int w = tid >> 6, lane = tid & 63;
  const int mh = w & 1, nh = w >> 1;
  const int c16 = lane & 15, quad = lane >> 4;
  const int rowbase = blockIdx.x * BN;

  // Per-lane pre-swizzled source offsets for B staging (t-independent).
  int soff[4];
#pragma unroll
  for (int i = 0; i < 4; ++i) {
    int o = w * 4096 + i * 1024 + lane * 16;
    int row = o >> 8, inrow = o & 255;
    soff[i] = row * 256 + (inrow ^ ((row & 7) << 4));
  }
  const int stoff = w * 4096;   // wave-uniform LDS base within buffer

  // Tile-0 B stage into B0 (in flight across z staging; disjoint from zhS=B1).
#pragma unroll
  for (int i = 0; i < 4; ++i)
    GLDS16((const char*)cbh + soff[i], B0 + stoff + i * 1024);

  // Stage z tile -> bf16 LDS (one time), into B1 region.
#pragma unroll
  for (int p = 0; p < 4; ++p) {
    int fid = p * 256 + tid;
    int row = fid >> 4, c8 = fid & 15;
    float4 a = reinterpret_cast<const float4*>(ze)[(size_t)(rowbase + row) * 32 + c8 * 2];
    float4 b = reinterpret_cast<const float4*>(ze)[(size_t)(rowbase + row) * 32 + c8 * 2 + 1];
    ushort h[8] = {f2bf_rne(a.x), f2bf_rne(a.y), f2bf_rne(a.z), f2bf_rne(a.w),
                   f2bf_rne(b.x), f2bf_rne(b.y), f2bf_rne(b.z), f2bf_rne(b.w)};
    *reinterpret_cast<uint4*>(&zhS[row * 128 + ((c8 ^ (row & 7)) * 8)]) =
        *reinterpret_cast<const uint4*>(h);
  }
  // cbsq -> LDS (1024 floats).
  reinterpret_cast<float4*>(cbsqS)[tid] = reinterpret_cast<const float4*>(cbsq)[tid];
  __syncthreads();   // drains: tile-0 B stage + z writes + cbsq

  // Hoist A-frags from zhS(=B1): afrag[m2][ks].
  const int xk = c16 & 7;
  bf16x8 afrag[2][4];
#pragma unroll
  for (int m2 = 0; m2 < 2; ++m2) {
    int r = (mh * 32 + m2 * 16 + c16) * 128;
#pragma unroll
    for (int ks = 0; ks < 4; ++ks)
      afrag[m2][ks] = *reinterpret_cast<const bf16x8*>(&zhS[r + ((ks * 4 + quad) ^ xk) * 8]);
  }
  __syncthreads();   // zhS dead -> B1 may now be staged into

  unsigned t3[8][3];
#pragma unroll
  for (int s = 0; s < 8; ++s) { t3[s][0] = 0xFFFFFFFFu; t3[s][1] = 0xFFFFFFFFu; t3[s][2] = 0xFFFFFFFFu; }

  const int cbase = nh * 32 + c16;
  const char* cur = B0;
  char* nxt = B1;

  for (int t = 0; t < NTILE; ++t) {
    if (t + 1 < NTILE) {
#pragma unroll
      for (int i = 0; i < 4; ++i)
        GLDS16((const char*)cbh + (size_t)(t + 1) * 16384 + soff[i], nxt + stoff + i * 1024);
    }

    bf16x8 bf[2][4];
#pragma unroll
    for (int n2 = 0; n2 < 2; ++n2) {
      int rb = (nh * 32 + n2 * 16 + c16) * 256;
#pragma unroll
      for (int ks = 0; ks < 4; ++ks)
        bf[n2][ks] = *reinterpret_cast<const bf16x8*>(cur + rb + (((ks * 4 + quad) ^ xk) << 4));
    }

    f32x4 acc[2][2];
#pragma unroll
    for (int m2 = 0; m2 < 2; ++m2)
#pragma unroll
      for (int n2 = 0; n2 < 2; ++n2) acc[m2][n2] = (f32x4){0.f, 0.f, 0.f, 0.f};

#pragma unroll
    for (int ks = 0; ks < 4; ++ks)
#pragma unroll
      for (int m2 = 0; m2 < 2; ++m2)
#pragma unroll
        for (int n2 = 0; n2 < 2; ++n2)
          acc[m2][n2] = __builtin_amdgcn_mfma_f32_16x16x32_bf16(afrag[m2][ks], bf[n2][ks], acc[m2][n2], 0, 0, 0);

    // keys + packed top-3. D layout: col=lane&15, row=quad*4+reg (m89).
#pragma unroll
    for (int n2 = 0; n2 < 2; ++n2) {
      int code = t * BT + cbase + n2 * 16;
      unsigned codeu = (unsigned)code & 1023u;          // pre-masked -> and_or
      float csb = cbsqS[code] + 192.0f;
#pragma unroll
      for (int m2 = 0; m2 < 2; ++m2)
#pragma unroll
        for (int reg = 0; reg < 4; ++reg) {
          float kf = fmaf(-2.f, acc[m2][n2][reg], csb);
          unsigned pk = (__float_as_uint(kf) & 0xFFFFFC00u) | codeu;
          int s = m2 * 4 + reg;
          unsigned n0 = min(t3[s][0], pk);
          unsigned n1 = med3u(t3[s][0], t3[s][1], pk);
          unsigned n2v = med3u(t3[s][1], t3[s][2], pk);
          t3[s][0] = n0; t3[s][1] = n1; t3[s][2] = n2v;
        }
    }

    __syncthreads();   // one barrier/tile: drains stage (vmcnt) + frag reads
    char* tmp = const_cast<char*>(cur); cur = nxt; nxt = tmp;
  }

  // Pool: 32 (nh,c16) groups x top-3 = 96 packed keys per row.
#pragma unroll
  for (int s = 0; s < 8; ++s) {
    int row = mh * 32 + (s >> 2) * 16 + quad * 4 + (s & 3);
    int col = (nh * 16 + c16) * 3;
    pool[row * 97 + col] = t3[s][0];
    pool[row * 97 + col + 1] = t3[s][1];
    pool[row * 97 + col + 2] = t3[s][2];
  }
  __syncthreads();
  if (tid < BN) {
    unsigned k[8];
#pragma unroll
    for (int q = 0; q < 8; ++q) k[q] = 0xFFFFFFFFu;
    for (int p = 0; p < 96; ++p) {
      unsigned v = pool[tid * 97 + p];
      if (v < k[7]) {
        k[7] = v;
#pragma unroll
        for (int q = 7; q > 0; --q)
          if (k[q] < k[q - 1]) { unsigned tk = k[q]; k[q] = k[q - 1]; k[q - 1] = tk; }
      }
    }
    uint4 cw;
    cw.x = (k[0] & 1023u) | ((k[1] & 1023u) << 16);
    cw.y = (k[2] & 1023u) | ((k[3] & 1023u) << 16);
    cw.z = (k[4] & 1023u) | ((k[5] & 1023u) << 16);
    cw.w = (k[6] & 1023u) | ((k[7] & 1023u) << 16);
    reinterpret_cast<uint4*>(cand)[rowbase + tid] = cw;
  }
}

// ---------------------------------------------------------------------------
// Rescore (R3/R7-verified core math UNTOUCHED): np fp32 key replication
//   key = fl32( fl32( zs - fl32(2*cross_fp64) ) + cb_sq32 ), tie -> low idx.
// Finalize folded in: fp64 device atomicAdd + last-block-done writes loss
// (sum-order change ~1e-15 relative — far below tolerance).
// ---------------------------------------------------------------------------
__global__ __launch_bounds__(256) void rescore_kernel(
    const float* __restrict__ ze, const float* __restrict__ cb,
    const float* __restrict__ cbsq, const ushort* __restrict__ cand,
    float* __restrict__ zq, float* __restrict__ idx_f,
    float* __restrict__ out_loss, double* __restrict__ acc,
    unsigned* __restrict__ cnt) {
  int w = threadIdx.x >> 6, lane = threadIdx.x & 63;
  int row = blockIdx.x * NROW_B + w;
  int g = lane >> 3, e = lane & 7;
  int myc = cand[(size_t)row * 8 + g];

  float2 z2 = reinterpret_cast<const float2*>(ze)[(size_t)row * 64 + lane];
  double zsum = (double)z2.x * (double)z2.x + (double)z2.y * (double)z2.y;
#pragma unroll
  for (int off = 32; off >= 1; off >>= 1) zsum += __shfl_xor(zsum, off, 64);
  float zs = (float)zsum;

  const float4* zrow4 = reinterpret_cast<const float4*>(ze + (size_t)row * C_DIM);
  const float4* crow4 = reinterpret_cast<const float4*>(cb + (size_t)myc * C_DIM);
  double p = 0.0;
#pragma unroll
  for (int q = 0; q < 4; ++q) {
    float4 zz = zrow4[e * 4 + q];
    float4 cc = crow4[e * 4 + q];
    p += (double)zz.x * (double)cc.x + (double)zz.y * (double)cc.y +
         (double)zz.z * (double)cc.z + (double)zz.w * (double)cc.w;
  }
  p += __shfl_xor(p, 1, 64);
  p += __shfl_xor(p, 2, 64);
  p += __shfl_xor(p, 4, 64);

  float tt = (float)(2.0 * p);
  float u = zs - tt;
  float d = u + cbsq[myc];

  float best = 3.4e38f;
  int bidx = K_CB + 1;
#pragma unroll
  for (int gg = 0; gg < 8; ++gg) {
    float dg = __shfl(d, gg * 8, 64);
    int ig = __shfl(myc, gg * 8, 64);
    if (dg < best || (dg == best && ig < bidx)) { best = dg; bidx = ig; }
  }

  float2 c2 = reinterpret_cast<const float2*>(cb)[(size_t)bidx * 64 + lane];
  reinterpret_cast<float2*>(zq)[(size_t)row * 64 + lane] = c2;

  double dx = (double)z2.x - (double)c2.x;
  double dy = (double)z2.y - (double)c2.y;
  double l = dx * dx + dy * dy;
#pragma unroll
  for (int off = 32; off >= 1; off >>= 1) l += __shfl_xor(l, off, 64);

  __shared__ double sh[NROW_B];
  if (lane == 0) { idx_f[row] = (float)bidx; sh[w] = l; }
  __syncthreads();
  if (threadIdx.x == 0) {
    double tot = sh[0] + sh[1] + sh[2] + sh[3];
    atomicAdd(acc, tot);
    __threadfence();
    unsigned old = atomicAdd(cnt, 1u);
    if (old == (unsigned)(NBLK_B - 1)) {
      __threadfence();
      double a = atomicAdd(acc, 0.0);   // atomic read: all adds landed in L2
      double mse = a / (double)((size_t)N_TOT * C_DIM);
      *out_loss = (float)(1.75 * mse);  // 0.75*q_latent + e_latent, both == mse
    }
  }
}

// ---------------------------------------------------------------------------
extern "C" void kernel_launch(void* const* d_in, const int* in_sizes, int n_in,
                              void* d_out, int out_size, void* d_ws, size_t ws_size,
                              hipStream_t stream) {
  const float* ze = (const float*)d_in[0];
  const float* cb = (const float*)d_in[1];

  float* out = (float*)d_out;
  float* zq = out;                                   // [N*C]
  float* out_loss = out + (size_t)N_TOT * C_DIM;     // [1]
  float* idx_f = out_loss + 1;                       // [N]

  float* cbsq = (float*)d_ws;                             // 4 KB @0
  ushort* cbh = (ushort*)((char*)d_ws + 8192);            // 256 KB
  ushort* cand = (ushort*)((char*)d_ws + 270336);         // 1 MB
  double* acc = (double*)((char*)d_ws + 1318912);         // 8 B
  unsigned* cnt = (unsigned*)((char*)d_ws + 1318920);     // 4 B

  prep_kernel<<<K_CB / 4, 256, 0, stream>>>(cb, cbsq, cbh, acc, cnt);
  dist_mfma_kernel<<<N_TOT / BN, 256, 0, stream>>>(ze, cbh, cbsq, cand);
  rescore_kernel<<<NBLK_B, 256, 0, stream>>>(ze, cb, cbsq, cand, zq, idx_f,
                                             out_loss, acc, cnt);
}

// Round 4
// 165.721 us; speedup vs baseline: 3.3658x; 3.3658x over previous
//
#include <hip/hip_runtime.h>

#define N_TOT 65536
#define C_DIM 128
#define K_CB  1024
#define BN 64
#define BT 64
#define NTILE (K_CB / BT)
#define NROW_B 4
#define NBLK_B (N_TOT / NROW_B)

typedef __attribute__((ext_vector_type(8))) short bf16x8;   // 8 bf16 = 4 VGPR
typedef __attribute__((ext_vector_type(4))) float f32x4;

__device__ __forceinline__ ushort f2bf_rne(float f) {
  unsigned u = __float_as_uint(f);
  return (ushort)((u + 0x7FFFu + ((u >> 16) & 1u)) >> 16);
}

// med3u(a,b,c) = median — inserting pk into sorted (t0<=t1<=t2) yields
// {min(t0,pk), med3(t0,t1,pk), med3(t1,t2,pk)} : 3 VALU vs 5-op min/max chain.
__device__ __forceinline__ unsigned med3u(unsigned a, unsigned b, unsigned c) {
  unsigned d;
  asm("v_med3_u32 %0, %1, %2, %3" : "=v"(d) : "v"(a), "v"(b), "v"(c));
  return d;
}

#define GLDS16(src, dst)                                                       \
  __builtin_amdgcn_global_load_lds(                                            \
      (const __attribute__((address_space(1))) void*)(src),                    \
      (__attribute__((address_space(3))) void*)(dst), 16, 0, 0)

// ---------------------------------------------------------------------------
// prep = cbsq (fp64 row sumsq, frozen math) + cbconv (bf16 RNE, same layout).
// NO global atomics (R3 lesson: 16384-way contended fp64 CAS = +400 µs).
// ---------------------------------------------------------------------------
__global__ __launch_bounds__(256) void prep_kernel(
    const float* __restrict__ cb, float* __restrict__ cbsq,
    ushort* __restrict__ cbh) {
  int w = threadIdx.x >> 6, lane = threadIdx.x & 63;
  int r = blockIdx.x * 4 + w;
  float2 v = reinterpret_cast<const float2*>(cb + (size_t)r * C_DIM)[lane];
  ushort2 h;
  h.x = f2bf_rne(v.x); h.y = f2bf_rne(v.y);
  reinterpret_cast<ushort2*>(cbh + (size_t)r * C_DIM)[lane] = h;
  double s = (double)v.x * (double)v.x + (double)v.y * (double)v.y;
#pragma unroll
  for (int off = 32; off >= 1; off >>= 1) s += __shfl_xor(s, off, 64);
  if (lane == 0) cbsq[r] = (float)s;
}

// ---------------------------------------------------------------------------
// MFMA filter (R3 structure, kept): LDS 36864 (4 blocks/CU), B tile staged
// via global_load_lds w=16 double-buffered, source-side XOR swizzle, med3
// top-3 insert. Pool stride 97, top-8 rescue unchanged (verified).
// ---------------------------------------------------------------------------
__global__ __launch_bounds__(256, 4) void dist_mfma_kernel(
    const float* __restrict__ ze, const ushort* __restrict__ cbh,
    const float* __restrict__ cbsq, ushort* __restrict__ cand) {
  // [B0 16K | B1 16K (zh aliases) | cbsq 4K]; pool[24832] aliases B0+B1 head.
  __shared__ __align__(16) char smem[36864];
  char* const B0 = smem;
  char* const B1 = smem + 16384;
  ushort* zhS = reinterpret_cast<ushort*>(B1);            // [64][128] xor-swz
  unsigned* pool = reinterpret_cast<unsigned*>(smem);     // [64][97]
  float* const cbsqS = reinterpret_cast<float*>(smem + 32768);

  const int tid = threadIdx.x;
  const int w = tid >> 6, lane = tid & 63;
  const int mh = w & 1, nh = w >> 1;
  const int c16 = lane & 15, quad = lane >> 4;
  const int rowbase = blockIdx.x * BN;

  // Per-lane pre-swizzled source offsets for B staging (t-independent).
  int soff[4];
#pragma unroll
  for (int i = 0; i < 4; ++i) {
    int o = w * 4096 + i * 1024 + lane * 16;
    int row = o >> 8, inrow = o & 255;
    soff[i] = row * 256 + (inrow ^ ((row & 7) << 4));
  }
  const int stoff = w * 4096;   // wave-uniform LDS base within buffer

  // Tile-0 B stage into B0 (in flight across z staging; disjoint from zhS=B1).
#pragma unroll
  for (int i = 0; i < 4; ++i)
    GLDS16((const char*)cbh + soff[i], B0 + stoff + i * 1024);

  // Stage z tile -> bf16 LDS (one time), into B1 region.
#pragma unroll
  for (int p = 0; p < 4; ++p) {
    int fid = p * 256 + tid;
    int row = fid >> 4, c8 = fid & 15;
    float4 a = reinterpret_cast<const float4*>(ze)[(size_t)(rowbase + row) * 32 + c8 * 2];
    float4 b = reinterpret_cast<const float4*>(ze)[(size_t)(rowbase + row) * 32 + c8 * 2 + 1];
    ushort h[8] = {f2bf_rne(a.x), f2bf_rne(a.y), f2bf_rne(a.z), f2bf_rne(a.w),
                   f2bf_rne(b.x), f2bf_rne(b.y), f2bf_rne(b.z), f2bf_rne(b.w)};
    *reinterpret_cast<uint4*>(&zhS[row * 128 + ((c8 ^ (row & 7)) * 8)]) =
        *reinterpret_cast<const uint4*>(h);
  }
  // cbsq -> LDS (1024 floats).
  reinterpret_cast<float4*>(cbsqS)[tid] = reinterpret_cast<const float4*>(cbsq)[tid];
  __syncthreads();   // drains: tile-0 B stage + z writes + cbsq

  // Hoist A-frags from zhS(=B1): afrag[m2][ks].
  const int xk = c16 & 7;
  bf16x8 afrag[2][4];
#pragma unroll
  for (int m2 = 0; m2 < 2; ++m2) {
    int r = (mh * 32 + m2 * 16 + c16) * 128;
#pragma unroll
    for (int ks = 0; ks < 4; ++ks)
      afrag[m2][ks] = *reinterpret_cast<const bf16x8*>(&zhS[r + ((ks * 4 + quad) ^ xk) * 8]);
  }
  __syncthreads();   // zhS dead -> B1 may now be staged into

  unsigned t3[8][3];
#pragma unroll
  for (int s = 0; s < 8; ++s) { t3[s][0] = 0xFFFFFFFFu; t3[s][1] = 0xFFFFFFFFu; t3[s][2] = 0xFFFFFFFFu; }

  const int cbase = nh * 32 + c16;
  const char* cur = B0;
  char* nxt = B1;

  for (int t = 0; t < NTILE; ++t) {
    if (t + 1 < NTILE) {
#pragma unroll
      for (int i = 0; i < 4; ++i)
        GLDS16((const char*)cbh + (size_t)(t + 1) * 16384 + soff[i], nxt + stoff + i * 1024);
    }

    bf16x8 bf[2][4];
#pragma unroll
    for (int n2 = 0; n2 < 2; ++n2) {
      int rb = (nh * 32 + n2 * 16 + c16) * 256;
#pragma unroll
      for (int ks = 0; ks < 4; ++ks)
        bf[n2][ks] = *reinterpret_cast<const bf16x8*>(cur + rb + (((ks * 4 + quad) ^ xk) << 4));
    }

    f32x4 acc[2][2];
#pragma unroll
    for (int m2 = 0; m2 < 2; ++m2)
#pragma unroll
      for (int n2 = 0; n2 < 2; ++n2) acc[m2][n2] = (f32x4){0.f, 0.f, 0.f, 0.f};

#pragma unroll
    for (int ks = 0; ks < 4; ++ks)
#pragma unroll
      for (int m2 = 0; m2 < 2; ++m2)
#pragma unroll
        for (int n2 = 0; n2 < 2; ++n2)
          acc[m2][n2] = __builtin_amdgcn_mfma_f32_16x16x32_bf16(afrag[m2][ks], bf[n2][ks], acc[m2][n2], 0, 0, 0);

    // keys + packed top-3. D layout: col=lane&15, row=quad*4+reg (m89).
#pragma unroll
    for (int n2 = 0; n2 < 2; ++n2) {
      int code = t * BT + cbase + n2 * 16;
      unsigned codeu = (unsigned)code & 1023u;
      float csb = cbsqS[code] + 192.0f;
#pragma unroll
      for (int m2 = 0; m2 < 2; ++m2)
#pragma unroll
        for (int reg = 0; reg < 4; ++reg) {
          float kf = fmaf(-2.f, acc[m2][n2][reg], csb);
          unsigned pk = (__float_as_uint(kf) & 0xFFFFFC00u) | codeu;
          int s = m2 * 4 + reg;
          unsigned n0 = min(t3[s][0], pk);
          unsigned n1 = med3u(t3[s][0], t3[s][1], pk);
          unsigned n2v = med3u(t3[s][1], t3[s][2], pk);
          t3[s][0] = n0; t3[s][1] = n1; t3[s][2] = n2v;
        }
    }

    __syncthreads();   // one barrier/tile: drains stage (vmcnt) + frag reads
    char* tmp = const_cast<char*>(cur); cur = nxt; nxt = tmp;
  }

  // Pool: 32 (nh,c16) groups x top-3 = 96 packed keys per row.
#pragma unroll
  for (int s = 0; s < 8; ++s) {
    int row = mh * 32 + (s >> 2) * 16 + quad * 4 + (s & 3);
    int col = (nh * 16 + c16) * 3;
    pool[row * 97 + col] = t3[s][0];
    pool[row * 97 + col + 1] = t3[s][1];
    pool[row * 97 + col + 2] = t3[s][2];
  }
  __syncthreads();
  if (tid < BN) {
    unsigned k[8];
#pragma unroll
    for (int q = 0; q < 8; ++q) k[q] = 0xFFFFFFFFu;
    for (int p = 0; p < 96; ++p) {
      unsigned v = pool[tid * 97 + p];
      if (v < k[7]) {
        k[7] = v;
#pragma unroll
        for (int q = 7; q > 0; --q)
          if (k[q] < k[q - 1]) { unsigned tk = k[q]; k[q] = k[q - 1]; k[q - 1] = tk; }
      }
    }
    uint4 cw;
    cw.x = (k[0] & 1023u) | ((k[1] & 1023u) << 16);
    cw.y = (k[2] & 1023u) | ((k[3] & 1023u) << 16);
    cw.z = (k[4] & 1023u) | ((k[5] & 1023u) << 16);
    cw.w = (k[6] & 1023u) | ((k[7] & 1023u) << 16);
    reinterpret_cast<uint4*>(cand)[rowbase + tid] = cw;
  }
}

// ---------------------------------------------------------------------------
// Rescore (R2-verified form restored): per-block partial[] store, NO global
// atomics. key = fl32( fl32( zs - fl32(2*cross_fp64) ) + cb_sq32 ), tie->low.
// ---------------------------------------------------------------------------
__global__ __launch_bounds__(256) void rescore_kernel(
    const float* __restrict__ ze, const float* __restrict__ cb,
    const float* __restrict__ cbsq, const ushort* __restrict__ cand,
    float* __restrict__ zq, float* __restrict__ idx_f,
    double* __restrict__ partial) {
  int w = threadIdx.x >> 6, lane = threadIdx.x & 63;
  int row = blockIdx.x * NROW_B + w;
  int g = lane >> 3, e = lane & 7;
  int myc = cand[(size_t)row * 8 + g];

  float2 z2 = reinterpret_cast<const float2*>(ze)[(size_t)row * 64 + lane];
  double zsum = (double)z2.x * (double)z2.x + (double)z2.y * (double)z2.y;
#pragma unroll
  for (int off = 32; off >= 1; off >>= 1) zsum += __shfl_xor(zsum, off, 64);
  float zs = (float)zsum;

  const float4* zrow4 = reinterpret_cast<const float4*>(ze + (size_t)row * C_DIM);
  const float4* crow4 = reinterpret_cast<const float4*>(cb + (size_t)myc * C_DIM);
  double p = 0.0;
#pragma unroll
  for (int q = 0; q < 4; ++q) {
    float4 zz = zrow4[e * 4 + q];
    float4 cc = crow4[e * 4 + q];
    p += (double)zz.x * (double)cc.x + (double)zz.y * (double)cc.y +
         (double)zz.z * (double)cc.z + (double)zz.w * (double)cc.w;
  }
  p += __shfl_xor(p, 1, 64);
  p += __shfl_xor(p, 2, 64);
  p += __shfl_xor(p, 4, 64);

  float tt = (float)(2.0 * p);
  float u = zs - tt;
  float d = u + cbsq[myc];

  float best = 3.4e38f;
  int bidx = K_CB + 1;
#pragma unroll
  for (int gg = 0; gg < 8; ++gg) {
    float dg = __shfl(d, gg * 8, 64);
    int ig = __shfl(myc, gg * 8, 64);
    if (dg < best || (dg == best && ig < bidx)) { best = dg; bidx = ig; }
  }

  float2 c2 = reinterpret_cast<const float2*>(cb)[(size_t)bidx * 64 + lane];
  reinterpret_cast<float2*>(zq)[(size_t)row * 64 + lane] = c2;

  double dx = (double)z2.x - (double)c2.x;
  double dy = (double)z2.y - (double)c2.y;
  double l = dx * dx + dy * dy;
#pragma unroll
  for (int off = 32; off >= 1; off >>= 1) l += __shfl_xor(l, off, 64);

  __shared__ double sh[NROW_B];
  if (lane == 0) { idx_f[row] = (float)bidx; sh[w] = l; }
  __syncthreads();
  if (threadIdx.x == 0) partial[blockIdx.x] = sh[0] + sh[1] + sh[2] + sh[3];
}

__global__ __launch_bounds__(256) void finalize_kernel(
    const double* __restrict__ partial, float* __restrict__ out_loss) {
  double s = 0.0;
  for (int i = threadIdx.x; i < NBLK_B; i += 256) s += partial[i];
#pragma unroll
  for (int off = 32; off >= 1; off >>= 1) s += __shfl_down(s, off, 64);
  __shared__ double sh[4];
  int wv = threadIdx.x >> 6, lane = threadIdx.x & 63;
  if (lane == 0) sh[wv] = s;
  __syncthreads();
  if (threadIdx.x == 0) {
    double tot = sh[0] + sh[1] + sh[2] + sh[3];
    double mse = tot / (double)((size_t)N_TOT * C_DIM);
    *out_loss = (float)(1.75 * mse);  // 0.75*q_latent + e_latent, both == mse
  }
}

// ---------------------------------------------------------------------------
extern "C" void kernel_launch(void* const* d_in, const int* in_sizes, int n_in,
                              void* d_out, int out_size, void* d_ws, size_t ws_size,
                              hipStream_t stream) {
  const float* ze = (const float*)d_in[0];
  const float* cb = (const float*)d_in[1];

  float* out = (float*)d_out;
  float* zq = out;                                   // [N*C]
  float* out_loss = out + (size_t)N_TOT * C_DIM;     // [1]
  float* idx_f = out_loss + 1;                       // [N]

  float* cbsq = (float*)d_ws;                             // 4 KB @0
  ushort* cbh = (ushort*)((char*)d_ws + 8192);            // 256 KB
  ushort* cand = (ushort*)((char*)d_ws + 270336);         // 1 MB
  double* partial = (double*)((char*)d_ws + 1318912);     // 128 KB

  prep_kernel<<<K_CB / 4, 256, 0, stream>>>(cb, cbsq, cbh);
  dist_mfma_kernel<<<N_TOT / BN, 256, 0, stream>>>(ze, cbh, cbsq, cand);
  rescore_kernel<<<NBLK_B, 256, 0, stream>>>(ze, cb, cbsq, cand, zq, idx_f, partial);
  finalize_kernel<<<1, 256, 0, stream>>>(partial, out_loss);
}

// Round 5
// 159.246 us; speedup vs baseline: 3.5026x; 1.0407x over previous
//
#include <hip/hip_runtime.h>

#define N_TOT 65536
#define C_DIM 128
#define K_CB  1024
#define BN 64
#define BT 64
#define NTILE (K_CB / BT)
#define ROWS_BLK 8                     // rescore: 4 waves x 2 rows
#define NBLK_R (N_TOT / ROWS_BLK)      // 8192

typedef __attribute__((ext_vector_type(8))) short bf16x8;   // 8 bf16 = 4 VGPR
typedef __attribute__((ext_vector_type(4))) float f32x4;

__device__ __forceinline__ ushort f2bf_rne(float f) {
  unsigned u = __float_as_uint(f);
  return (ushort)((u + 0x7FFFu + ((u >> 16) & 1u)) >> 16);
}

// med3u: inserting pk into sorted (t0<=t1<=t2) -> {min, med3, med3}: 3 VALU.
__device__ __forceinline__ unsigned med3u(unsigned a, unsigned b, unsigned c) {
  unsigned d;
  asm("v_med3_u32 %0, %1, %2, %3" : "=v"(d) : "v"(a), "v"(b), "v"(c));
  return d;
}

#define GLDS16(src, dst)                                                       \
  __builtin_amdgcn_global_load_lds(                                            \
      (const __attribute__((address_space(1))) void*)(src),                    \
      (__attribute__((address_space(3))) void*)(dst), 16, 0, 0)

// ---------------------------------------------------------------------------
// prep = cbsq (fp64 row sumsq, frozen math) + cbconv (bf16 RNE, same layout).
// NO global atomics (R3 lesson: 16384-way contended fp64 CAS = +400 µs).
// ---------------------------------------------------------------------------
__global__ __launch_bounds__(256) void prep_kernel(
    const float* __restrict__ cb, float* __restrict__ cbsq,
    ushort* __restrict__ cbh) {
  int w = threadIdx.x >> 6, lane = threadIdx.x & 63;
  int r = blockIdx.x * 4 + w;
  float2 v = reinterpret_cast<const float2*>(cb + (size_t)r * C_DIM)[lane];
  ushort2 h;
  h.x = f2bf_rne(v.x); h.y = f2bf_rne(v.y);
  reinterpret_cast<ushort2*>(cbh + (size_t)r * C_DIM)[lane] = h;
  double s = (double)v.x * (double)v.x + (double)v.y * (double)v.y;
#pragma unroll
  for (int off = 32; off >= 1; off >>= 1) s += __shfl_xor(s, off, 64);
  if (lane == 0) cbsq[r] = (float)s;
}

// ---------------------------------------------------------------------------
// MFMA filter, R5: cross-tile sort defer.
//  - R4 timeline per tile was serial: ds_read -> lgkm wait -> MFMA -> sort.
//    Now sort(tile t-1) issues alongside stage(t+1) + ds_read(t): sort VALU
//    fills the LDS-read latency window (the largest per-tile pipe cost).
//  - acc ping-pong accA/accB across one barrier (+16 VGPR); static B0/B1
//    addressing (no pointer swap). Math/order of candidate keys unchanged.
//  - LDS 36864 (4 blocks/CU), source-side XOR swizzle, med3 insert: kept.
// ---------------------------------------------------------------------------
__global__ __launch_bounds__(256, 4) void dist_mfma_kernel(
    const float* __restrict__ ze, const ushort* __restrict__ cbh,
    const float* __restrict__ cbsq, ushort* __restrict__ cand) {
  // [B0 16K | B1 16K (zh aliases) | cbsq 4K]; pool[24832] aliases B0+B1 head.
  __shared__ __align__(16) char smem[36864];
  char* const B0 = smem;
  char* const B1 = smem + 16384;
  ushort* zhS = reinterpret_cast<ushort*>(B1);            // [64][128] xor-swz
  unsigned* pool = reinterpret_cast<unsigned*>(smem);     // [64][97]
  float* const cbsqS = reinterpret_cast<float*>(smem + 32768);

  const int tid = threadIdx.x;
  const int w = tid >> 6, lane = tid & 63;
  const int mh = w & 1, nh = w >> 1;
  const int c16 = lane & 15, quad = lane >> 4;
  const int rowbase = blockIdx.x * BN;

  // Per-lane pre-swizzled source offsets for B staging (t-independent).
  int soff[4];
#pragma unroll
  for (int i = 0; i < 4; ++i) {
    int o = w * 4096 + i * 1024 + lane * 16;
    int row = o >> 8, inrow = o & 255;
    soff[i] = row * 256 + (inrow ^ ((row & 7) << 4));
  }
  const int stoff = w * 4096;   // wave-uniform LDS base within buffer

  // Tile-0 B stage into B0 (in flight across z staging; disjoint from zhS=B1).
#pragma unroll
  for (int i = 0; i < 4; ++i)
    GLDS16((const char*)cbh + soff[i], B0 + stoff + i * 1024);

  // Stage z tile -> bf16 LDS (one time), into B1 region.
#pragma unroll
  for (int p = 0; p < 4; ++p) {
    int fid = p * 256 + tid;
    int row = fid >> 4, c8 = fid & 15;
    float4 a = reinterpret_cast<const float4*>(ze)[(size_t)(rowbase + row) * 32 + c8 * 2];
    float4 b = reinterpret_cast<const float4*>(ze)[(size_t)(rowbase + row) * 32 + c8 * 2 + 1];
    ushort h[8] = {f2bf_rne(a.x), f2bf_rne(a.y), f2bf_rne(a.z), f2bf_rne(a.w),
                   f2bf_rne(b.x), f2bf_rne(b.y), f2bf_rne(b.z), f2bf_rne(b.w)};
    *reinterpret_cast<uint4*>(&zhS[row * 128 + ((c8 ^ (row & 7)) * 8)]) =
        *reinterpret_cast<const uint4*>(h);
  }
  // cbsq -> LDS (1024 floats).
  reinterpret_cast<float4*>(cbsqS)[tid] = reinterpret_cast<const float4*>(cbsq)[tid];
  __syncthreads();   // #1: tile-0 B stage + z writes + cbsq all visible

  // Hoist A-frags from zhS(=B1): afrag[m2][ks].
  const int xk = c16 & 7;
  bf16x8 afrag[2][4];
#pragma unroll
  for (int m2 = 0; m2 < 2; ++m2) {
    int r = (mh * 32 + m2 * 16 + c16) * 128;
#pragma unroll
    for (int ks = 0; ks < 4; ++ks)
      afrag[m2][ks] = *reinterpret_cast<const bf16x8*>(&zhS[r + ((ks * 4 + quad) ^ xk) * 8]);
  }
  __syncthreads();   // #2: zhS dead -> B1 stageable

  unsigned t3[8][3];
#pragma unroll
  for (int s = 0; s < 8; ++s) { t3[s][0] = 0xFFFFFFFFu; t3[s][1] = 0xFFFFFFFFu; t3[s][2] = 0xFFFFFFFFu; }

  const int cbase = nh * 32 + c16;

  auto STAGE = [&](int t, char* dst) {
#pragma unroll
    for (int i = 0; i < 4; ++i)
      GLDS16((const char*)cbh + (size_t)t * 16384 + soff[i], dst + stoff + i * 1024);
  };
  auto READ_MFMA = [&](const char* buf, f32x4 (&acc)[2][2]) {
    bf16x8 bf[2][4];
#pragma unroll
    for (int n2 = 0; n2 < 2; ++n2) {
      int rb = (nh * 32 + n2 * 16 + c16) * 256;
#pragma unroll
      for (int ks = 0; ks < 4; ++ks)
        bf[n2][ks] = *reinterpret_cast<const bf16x8*>(buf + rb + (((ks * 4 + quad) ^ xk) << 4));
    }
#pragma unroll
    for (int m2 = 0; m2 < 2; ++m2)
#pragma unroll
      for (int n2 = 0; n2 < 2; ++n2) acc[m2][n2] = (f32x4){0.f, 0.f, 0.f, 0.f};
#pragma unroll
    for (int ks = 0; ks < 4; ++ks)
#pragma unroll
      for (int m2 = 0; m2 < 2; ++m2)
#pragma unroll
        for (int n2 = 0; n2 < 2; ++n2)
          acc[m2][n2] = __builtin_amdgcn_mfma_f32_16x16x32_bf16(afrag[m2][ks], bf[n2][ks], acc[m2][n2], 0, 0, 0);
  };
  auto SORT = [&](const f32x4 (&acc)[2][2], int t) {
#pragma unroll
    for (int n2 = 0; n2 < 2; ++n2) {
      int code = t * BT + cbase + n2 * 16;
      unsigned codeu = (unsigned)code & 1023u;
      float csb = cbsqS[code] + 192.0f;
#pragma unroll
      for (int m2 = 0; m2 < 2; ++m2)
#pragma unroll
        for (int reg = 0; reg < 4; ++reg) {
          float kf = fmaf(-2.f, acc[m2][n2][reg], csb);
          unsigned pk = (__float_as_uint(kf) & 0xFFFFFC00u) | codeu;
          int s = m2 * 4 + reg;
          unsigned n0 = min(t3[s][0], pk);
          unsigned n1 = med3u(t3[s][0], t3[s][1], pk);
          unsigned n2v = med3u(t3[s][1], t3[s][2], pk);
          t3[s][0] = n0; t3[s][1] = n1; t3[s][2] = n2v;
        }
    }
  };

  f32x4 accA[2][2], accB[2][2];

  // tile 0 (B0 staged+drained at #1); stage tile 1 into B1.
  STAGE(1, B1);
  READ_MFMA(B0, accA);
  __syncthreads();   // #3: stage(1) drained; all B0 reads done

  for (int tp = 0; tp < 7; ++tp) {
    int t = 2 * tp + 1;                 // odd tile, lives in B1
    STAGE(t + 1, B0);                   // even tile -> B0
    SORT(accA, t - 1);                  // sort even tile t-1 (overlaps reads)
    READ_MFMA(B1, accB);                // tile t
    __syncthreads();
    STAGE(t + 2, B1);                   // odd tile -> B1
    SORT(accB, t);
    READ_MFMA(B0, accA);                // tile t+1
    __syncthreads();
  }
  // tiles 14 (accA, unsorted) and 15 (staged in B1, drained).
  SORT(accA, 14);
  READ_MFMA(B1, accB);
  SORT(accB, 15);
  __syncthreads();   // all waves done reading B0/B1 before pool overwrite

  // Pool: 32 (nh,c16) groups x top-3 = 96 packed keys per row.
#pragma unroll
  for (int s = 0; s < 8; ++s) {
    int row = mh * 32 + (s >> 2) * 16 + quad * 4 + (s & 3);
    int col = (nh * 16 + c16) * 3;
    pool[row * 97 + col] = t3[s][0];
    pool[row * 97 + col + 1] = t3[s][1];
    pool[row * 97 + col + 2] = t3[s][2];
  }
  __syncthreads();
  if (tid < BN) {
    unsigned k[8];
#pragma unroll
    for (int q = 0; q < 8; ++q) k[q] = 0xFFFFFFFFu;
    for (int p = 0; p < 96; ++p) {
      unsigned v = pool[tid * 97 + p];
      if (v < k[7]) {
        k[7] = v;
#pragma unroll
        for (int q = 7; q > 0; --q)
          if (k[q] < k[q - 1]) { unsigned tk = k[q]; k[q] = k[q - 1]; k[q - 1] = tk; }
      }
    }
    uint4 cw;
    cw.x = (k[0] & 1023u) | ((k[1] & 1023u) << 16);
    cw.y = (k[2] & 1023u) | ((k[3] & 1023u) << 16);
    cw.z = (k[4] & 1023u) | ((k[5] & 1023u) << 16);
    cw.w = (k[6] & 1023u) | ((k[7] & 1023u) << 16);
    reinterpret_cast<uint4*>(cand)[rowbase + tid] = cw;
  }
}

// ---------------------------------------------------------------------------
// Rescore, R5: 2 rows/wave (independent chains interleaved) + fp64 dot split
// into 2 partials. ALL fp32 rounding points preserved exactly:
//   zs = fl32(fp64 sum); tt = fl32(2*p64); u = zs - tt; d = u + cbsq32;
//   tie -> low idx. Loss: exact fp64 diffs, full-wave reduce (unchanged).
// ---------------------------------------------------------------------------
__global__ __launch_bounds__(256) void rescore_kernel(
    const float* __restrict__ ze, const float* __restrict__ cb,
    const float* __restrict__ cbsq, const ushort* __restrict__ cand,
    float* __restrict__ zq, float* __restrict__ idx_f,
    double* __restrict__ partial) {
  int w = threadIdx.x >> 6, lane = threadIdx.x & 63;
  int rbase = blockIdx.x * ROWS_BLK + w * 2;
  int g = lane >> 3, e = lane & 7;

  int myc[2];
  float2 z2[2];
  double zsum[2];
#pragma unroll
  for (int r = 0; r < 2; ++r) {
    myc[r] = cand[(size_t)(rbase + r) * 8 + g];
    z2[r] = reinterpret_cast<const float2*>(ze)[(size_t)(rbase + r) * 64 + lane];
    zsum[r] = (double)z2[r].x * (double)z2[r].x + (double)z2[r].y * (double)z2[r].y;
  }
#pragma unroll
  for (int off = 32; off >= 1; off >>= 1) {
    zsum[0] += __shfl_xor(zsum[0], off, 64);
    zsum[1] += __shfl_xor(zsum[1], off, 64);
  }

  double p[2];
#pragma unroll
  for (int r = 0; r < 2; ++r) {
    const float4* zr = reinterpret_cast<const float4*>(ze + (size_t)(rbase + r) * C_DIM);
    const float4* cr = reinterpret_cast<const float4*>(cb + (size_t)myc[r] * C_DIM);
    double p0 = 0.0, p1 = 0.0;
#pragma unroll
    for (int q = 0; q < 2; ++q) {
      float4 zz = zr[e * 4 + q];
      float4 cc = cr[e * 4 + q];
      p0 += (double)zz.x * (double)cc.x + (double)zz.y * (double)cc.y +
            (double)zz.z * (double)cc.z + (double)zz.w * (double)cc.w;
      float4 zz2 = zr[e * 4 + 2 + q];
      float4 cc2 = cr[e * 4 + 2 + q];
      p1 += (double)zz2.x * (double)cc2.x + (double)zz2.y * (double)cc2.y +
            (double)zz2.z * (double)cc2.z + (double)zz2.w * (double)cc2.w;
    }
    p[r] = p0 + p1;
  }
#pragma unroll
  for (int off = 1; off <= 4; off <<= 1) {
    p[0] += __shfl_xor(p[0], off, 64);
    p[1] += __shfl_xor(p[1], off, 64);
  }

  float d[2];
#pragma unroll
  for (int r = 0; r < 2; ++r) {
    float zs = (float)zsum[r];
    float tt = (float)(2.0 * p[r]);
    float u = zs - tt;
    d[r] = u + cbsq[myc[r]];
  }

  float best[2];
  int bidx[2];
#pragma unroll
  for (int r = 0; r < 2; ++r) { best[r] = 3.4e38f; bidx[r] = K_CB + 1; }
#pragma unroll
  for (int gg = 0; gg < 8; ++gg) {
#pragma unroll
    for (int r = 0; r < 2; ++r) {
      float dg = __shfl(d[r], gg * 8, 64);
      int ig = __shfl(myc[r], gg * 8, 64);
      if (dg < best[r] || (dg == best[r] && ig < bidx[r])) { best[r] = dg; bidx[r] = ig; }
    }
  }

  double l[2];
#pragma unroll
  for (int r = 0; r < 2; ++r) {
    float2 c2 = reinterpret_cast<const float2*>(cb)[(size_t)bidx[r] * 64 + lane];
    reinterpret_cast<float2*>(zq)[(size_t)(rbase + r) * 64 + lane] = c2;
    double dx = (double)z2[r].x - (double)c2.x;
    double dy = (double)z2[r].y - (double)c2.y;
    l[r] = dx * dx + dy * dy;
  }
#pragma unroll
  for (int off = 32; off >= 1; off >>= 1) {
    l[0] += __shfl_xor(l[0], off, 64);
    l[1] += __shfl_xor(l[1], off, 64);
  }

  __shared__ double sh[ROWS_BLK];
  if (lane == 0) {
    idx_f[rbase] = (float)bidx[0];
    idx_f[rbase + 1] = (float)bidx[1];
    sh[w * 2] = l[0];
    sh[w * 2 + 1] = l[1];
  }
  __syncthreads();
  if (threadIdx.x == 0) {
    partial[blockIdx.x] = ((sh[0] + sh[1]) + (sh[2] + sh[3])) +
                          ((sh[4] + sh[5]) + (sh[6] + sh[7]));
  }
}

__global__ __launch_bounds__(256) void finalize_kernel(
    const double* __restrict__ partial, float* __restrict__ out_loss) {
  double s = 0.0;
  for (int i = threadIdx.x; i < NBLK_R; i += 256) s += partial[i];
#pragma unroll
  for (int off = 32; off >= 1; off >>= 1) s += __shfl_down(s, off, 64);
  __shared__ double sh[4];
  int wv = threadIdx.x >> 6, lane = threadIdx.x & 63;
  if (lane == 0) sh[wv] = s;
  __syncthreads();
  if (threadIdx.x == 0) {
    double tot = sh[0] + sh[1] + sh[2] + sh[3];
    double mse = tot / (double)((size_t)N_TOT * C_DIM);
    *out_loss = (float)(1.75 * mse);  // 0.75*q_latent + e_latent, both == mse
  }
}

// ---------------------------------------------------------------------------
extern "C" void kernel_launch(void* const* d_in, const int* in_sizes, int n_in,
                              void* d_out, int out_size, void* d_ws, size_t ws_size,
                              hipStream_t stream) {
  const float* ze = (const float*)d_in[0];
  const float* cb = (const float*)d_in[1];

  float* out = (float*)d_out;
  float* zq = out;                                   // [N*C]
  float* out_loss = out + (size_t)N_TOT * C_DIM;     // [1]
  float* idx_f = out_loss + 1;                       // [N]

  float* cbsq = (float*)d_ws;                             // 4 KB @0
  ushort* cbh = (ushort*)((char*)d_ws + 8192);            // 256 KB
  ushort* cand = (ushort*)((char*)d_ws + 270336);         // 1 MB
  double* partial = (double*)((char*)d_ws + 1318912);     // 64 KB

  prep_kernel<<<K_CB / 4, 256, 0, stream>>>(cb, cbsq, cbh);
  dist_mfma_kernel<<<N_TOT / BN, 256, 0, stream>>>(ze, cbh, cbsq, cand);
  rescore_kernel<<<NBLK_R, 256, 0, stream>>>(ze, cb, cbsq, cand, zq, idx_f, partial);
  finalize_kernel<<<1, 256, 0, stream>>>(partial, out_loss);
}

// Round 6
// 151.336 us; speedup vs baseline: 3.6857x; 1.0523x over previous
//
#include <hip/hip_runtime.h>

#define N_TOT 65536
#define C_DIM 128
#define K_CB  1024
#define BN 64
#define BT 64
#define NTILE (K_CB / BT)
#define ROWS_BLK 8                     // rescore: 4 waves x 2 rows (halves)
#define NBLK_R (N_TOT / ROWS_BLK)      // 8192

typedef __attribute__((ext_vector_type(8))) short bf16x8;   // 8 bf16 = 4 VGPR
typedef __attribute__((ext_vector_type(4))) float f32x4;

__device__ __forceinline__ ushort f2bf_rne(float f) {
  unsigned u = __float_as_uint(f);
  return (ushort)((u + 0x7FFFu + ((u >> 16) & 1u)) >> 16);
}

// med3u: inserting pk into sorted (t0<=t1<=t2) -> {min, med3, med3}: 3 VALU.
__device__ __forceinline__ unsigned med3u(unsigned a, unsigned b, unsigned c) {
  unsigned d;
  asm("v_med3_u32 %0, %1, %2, %3" : "=v"(d) : "v"(a), "v"(b), "v"(c));
  return d;
}

#define GLDS16(src, dst)                                                       \
  __builtin_amdgcn_global_load_lds(                                            \
      (const __attribute__((address_space(1))) void*)(src),                    \
      (__attribute__((address_space(3))) void*)(dst), 16, 0, 0)

// ---------------------------------------------------------------------------
// prep = cbsq (fp64 row sumsq, frozen math) + cbconv (bf16 RNE, same layout).
// NO global atomics (R3 lesson: 16384-way contended fp64 CAS = +400 µs).
// ---------------------------------------------------------------------------
__global__ __launch_bounds__(256) void prep_kernel(
    const float* __restrict__ cb, float* __restrict__ cbsq,
    ushort* __restrict__ cbh) {
  int w = threadIdx.x >> 6, lane = threadIdx.x & 63;
  int r = blockIdx.x * 4 + w;
  float2 v = reinterpret_cast<const float2*>(cb + (size_t)r * C_DIM)[lane];
  ushort2 h;
  h.x = f2bf_rne(v.x); h.y = f2bf_rne(v.y);
  reinterpret_cast<ushort2*>(cbh + (size_t)r * C_DIM)[lane] = h;
  double s = (double)v.x * (double)v.x + (double)v.y * (double)v.y;
#pragma unroll
  for (int off = 32; off >= 1; off >>= 1) s += __shfl_xor(s, off, 64);
  if (lane == 0) cbsq[r] = (float)s;
}

// ---------------------------------------------------------------------------
// MFMA filter (R5 structure, UNTOUCHED this round): cross-tile sort defer,
// LDS 36864 (4 blocks/CU), source-side XOR swizzle, med3 insert.
// ---------------------------------------------------------------------------
__global__ __launch_bounds__(256, 4) void dist_mfma_kernel(
    const float* __restrict__ ze, const ushort* __restrict__ cbh,
    const float* __restrict__ cbsq, ushort* __restrict__ cand) {
  // [B0 16K | B1 16K (zh aliases) | cbsq 4K]; pool[24832] aliases B0+B1 head.
  __shared__ __align__(16) char smem[36864];
  char* const B0 = smem;
  char* const B1 = smem + 16384;
  ushort* zhS = reinterpret_cast<ushort*>(B1);            // [64][128] xor-swz
  unsigned* pool = reinterpret_cast<unsigned*>(smem);     // [64][97]
  float* const cbsqS = reinterpret_cast<float*>(smem + 32768);

  const int tid = threadIdx.x;
  const int w = tid >> 6, lane = tid & 63;
  const int mh = w & 1, nh = w >> 1;
  const int c16 = lane & 15, quad = lane >> 4;
  const int rowbase = blockIdx.x * BN;

  // Per-lane pre-swizzled source offsets for B staging (t-independent).
  int soff[4];
#pragma unroll
  for (int i = 0; i < 4; ++i) {
    int o = w * 4096 + i * 1024 + lane * 16;
    int row = o >> 8, inrow = o & 255;
    soff[i] = row * 256 + (inrow ^ ((row & 7) << 4));
  }
  const int stoff = w * 4096;   // wave-uniform LDS base within buffer

  // Tile-0 B stage into B0 (in flight across z staging; disjoint from zhS=B1).
#pragma unroll
  for (int i = 0; i < 4; ++i)
    GLDS16((const char*)cbh + soff[i], B0 + stoff + i * 1024);

  // Stage z tile -> bf16 LDS (one time), into B1 region.
#pragma unroll
  for (int p = 0; p < 4; ++p) {
    int fid = p * 256 + tid;
    int row = fid >> 4, c8 = fid & 15;
    float4 a = reinterpret_cast<const float4*>(ze)[(size_t)(rowbase + row) * 32 + c8 * 2];
    float4 b = reinterpret_cast<const float4*>(ze)[(size_t)(rowbase + row) * 32 + c8 * 2 + 1];
    ushort h[8] = {f2bf_rne(a.x), f2bf_rne(a.y), f2bf_rne(a.z), f2bf_rne(a.w),
                   f2bf_rne(b.x), f2bf_rne(b.y), f2bf_rne(b.z), f2bf_rne(b.w)};
    *reinterpret_cast<uint4*>(&zhS[row * 128 + ((c8 ^ (row & 7)) * 8)]) =
        *reinterpret_cast<const uint4*>(h);
  }
  // cbsq -> LDS (1024 floats).
  reinterpret_cast<float4*>(cbsqS)[tid] = reinterpret_cast<const float4*>(cbsq)[tid];
  __syncthreads();   // #1: tile-0 B stage + z writes + cbsq all visible

  // Hoist A-frags from zhS(=B1): afrag[m2][ks].
  const int xk = c16 & 7;
  bf16x8 afrag[2][4];
#pragma unroll
  for (int m2 = 0; m2 < 2; ++m2) {
    int r = (mh * 32 + m2 * 16 + c16) * 128;
#pragma unroll
    for (int ks = 0; ks < 4; ++ks)
      afrag[m2][ks] = *reinterpret_cast<const bf16x8*>(&zhS[r + ((ks * 4 + quad) ^ xk) * 8]);
  }
  __syncthreads();   // #2: zhS dead -> B1 stageable

  unsigned t3[8][3];
#pragma unroll
  for (int s = 0; s < 8; ++s) { t3[s][0] = 0xFFFFFFFFu; t3[s][1] = 0xFFFFFFFFu; t3[s][2] = 0xFFFFFFFFu; }

  const int cbase = nh * 32 + c16;

  auto STAGE = [&](int t, char* dst) {
#pragma unroll
    for (int i = 0; i < 4; ++i)
      GLDS16((const char*)cbh + (size_t)t * 16384 + soff[i], dst + stoff + i * 1024);
  };
  auto READ_MFMA = [&](const char* buf, f32x4 (&acc)[2][2]) {
    bf16x8 bf[2][4];
#pragma unroll
    for (int n2 = 0; n2 < 2; ++n2) {
      int rb = (nh * 32 + n2 * 16 + c16) * 256;
#pragma unroll
      for (int ks = 0; ks < 4; ++ks)
        bf[n2][ks] = *reinterpret_cast<const bf16x8*>(buf + rb + (((ks * 4 + quad) ^ xk) << 4));
    }
#pragma unroll
    for (int m2 = 0; m2 < 2; ++m2)
#pragma unroll
      for (int n2 = 0; n2 < 2; ++n2) acc[m2][n2] = (f32x4){0.f, 0.f, 0.f, 0.f};
#pragma unroll
    for (int ks = 0; ks < 4; ++ks)
#pragma unroll
      for (int m2 = 0; m2 < 2; ++m2)
#pragma unroll
        for (int n2 = 0; n2 < 2; ++n2)
          acc[m2][n2] = __builtin_amdgcn_mfma_f32_16x16x32_bf16(afrag[m2][ks], bf[n2][ks], acc[m2][n2], 0, 0, 0);
  };
  auto SORT = [&](const f32x4 (&acc)[2][2], int t) {
#pragma unroll
    for (int n2 = 0; n2 < 2; ++n2) {
      int code = t * BT + cbase + n2 * 16;
      unsigned codeu = (unsigned)code & 1023u;
      float csb = cbsqS[code] + 192.0f;
#pragma unroll
      for (int m2 = 0; m2 < 2; ++m2)
#pragma unroll
        for (int reg = 0; reg < 4; ++reg) {
          float kf = fmaf(-2.f, acc[m2][n2][reg], csb);
          unsigned pk = (__float_as_uint(kf) & 0xFFFFFC00u) | codeu;
          int s = m2 * 4 + reg;
          unsigned n0 = min(t3[s][0], pk);
          unsigned n1 = med3u(t3[s][0], t3[s][1], pk);
          unsigned n2v = med3u(t3[s][1], t3[s][2], pk);
          t3[s][0] = n0; t3[s][1] = n1; t3[s][2] = n2v;
        }
    }
  };

  f32x4 accA[2][2], accB[2][2];

  // tile 0 (B0 staged+drained at #1); stage tile 1 into B1.
  STAGE(1, B1);
  READ_MFMA(B0, accA);
  __syncthreads();   // #3: stage(1) drained; all B0 reads done

  for (int tp = 0; tp < 7; ++tp) {
    int t = 2 * tp + 1;                 // odd tile, lives in B1
    STAGE(t + 1, B0);                   // even tile -> B0
    SORT(accA, t - 1);                  // sort even tile t-1 (overlaps reads)
    READ_MFMA(B1, accB);                // tile t
    __syncthreads();
    STAGE(t + 2, B1);                   // odd tile -> B1
    SORT(accB, t);
    READ_MFMA(B0, accA);                // tile t+1
    __syncthreads();
  }
  // tiles 14 (accA, unsorted) and 15 (staged in B1, drained).
  SORT(accA, 14);
  READ_MFMA(B1, accB);
  SORT(accB, 15);
  __syncthreads();   // all waves done reading B0/B1 before pool overwrite

  // Pool: 32 (nh,c16) groups x top-3 = 96 packed keys per row.
#pragma unroll
  for (int s = 0; s < 8; ++s) {
    int row = mh * 32 + (s >> 2) * 16 + quad * 4 + (s & 3);
    int col = (nh * 16 + c16) * 3;
    pool[row * 97 + col] = t3[s][0];
    pool[row * 97 + col + 1] = t3[s][1];
    pool[row * 97 + col + 2] = t3[s][2];
  }
  __syncthreads();
  if (tid < BN) {
    unsigned k[8];
#pragma unroll
    for (int q = 0; q < 8; ++q) k[q] = 0xFFFFFFFFu;
    for (int p = 0; p < 96; ++p) {
      unsigned v = pool[tid * 97 + p];
      if (v < k[7]) {
        k[7] = v;
#pragma unroll
        for (int q = 7; q > 0; --q)
          if (k[q] < k[q - 1]) { unsigned tk = k[q]; k[q] = k[q - 1]; k[q - 1] = tk; }
      }
    }
    uint4 cw;
    cw.x = (k[0] & 1023u) | ((k[1] & 1023u) << 16);
    cw.y = (k[2] & 1023u) | ((k[3] & 1023u) << 16);
    cw.z = (k[4] & 1023u) | ((k[5] & 1023u) << 16);
    cw.w = (k[6] & 1023u) | ((k[7] & 1023u) << 16);
    reinterpret_cast<uint4*>(cand)[rowbase + tid] = cw;
  }
}

// ---------------------------------------------------------------------------
// Rescore, R6: shuffle diet (DS-pipe theory).
//  - One wave = 2 rows (one per 32-lane half). 4 lanes/candidate; lane e=sl&3
//    reads z/c float4s at e+4j (j=0..7) -> every 4-lane group holds the FULL
//    z row, so xor(1,2) gives complete zsum AND dot on all lanes: 2 steps
//    each (was 6 / 3).
//  - argmin over 8 candidates: 3-step lexicographic xor min-reduce (was a
//    serial 8-iter broadcast loop). Pairwise (d, idx) lexicographic min is
//    the total-order min == numpy first-min-index semantics.
//  - loss: single 6-step full-wave tree; stride-32 crossing merges the two
//    rows' sums for free.  26 DS ops / 2 rows vs R5's 92.
//  - fp32 rounding points preserved: zs=fl32(fp64 sum), tt=fl32(2*p64),
//    u=zs-tt, d=u+cbsq32, tie->low idx. Only fp64 add order changes (same
//    class as R5's accepted reassociation; absmax was bit-identical).
// ---------------------------------------------------------------------------
__global__ __launch_bounds__(256) void rescore_kernel(
    const float* __restrict__ ze, const float* __restrict__ cb,
    const float* __restrict__ cbsq, const ushort* __restrict__ cand,
    float* __restrict__ zq, float* __restrict__ idx_f,
    double* __restrict__ partial) {
  int w = threadIdx.x >> 6, lane = threadIdx.x & 63;
  int h = lane >> 5, sl = lane & 31;
  int row = blockIdx.x * ROWS_BLK + w * 2 + h;
  int g = sl >> 2, e = sl & 3;
  int myc = cand[(size_t)row * 8 + g];

  const float4* zr = reinterpret_cast<const float4*>(ze + (size_t)row * C_DIM);
  const float4* cr = reinterpret_cast<const float4*>(cb + (size_t)myc * C_DIM);

  double p0 = 0.0, p1 = 0.0, zs0 = 0.0, zs1 = 0.0;
#pragma unroll
  for (int j = 0; j < 8; ++j) {
    float4 zf = zr[e + 4 * j];
    float4 cf = cr[e + 4 * j];
    double a = ((double)zf.x * (double)cf.x + (double)zf.y * (double)cf.y) +
               ((double)zf.z * (double)cf.z + (double)zf.w * (double)cf.w);
    double b = ((double)zf.x * (double)zf.x + (double)zf.y * (double)zf.y) +
               ((double)zf.z * (double)zf.z + (double)zf.w * (double)zf.w);
    if (j & 1) { p1 += a; zs1 += b; } else { p0 += a; zs0 += b; }
  }
  double pp = p0 + p1;
  double zsum = zs0 + zs1;
  // 4-lane group reduce: each group holds the full row -> 2 steps complete both.
  pp += __shfl_xor(pp, 1, 64);
  pp += __shfl_xor(pp, 2, 64);
  zsum += __shfl_xor(zsum, 1, 64);
  zsum += __shfl_xor(zsum, 2, 64);

  float zs = (float)zsum;
  float tt = (float)(2.0 * pp);
  float u = zs - tt;
  float d = u + cbsq[myc];

  // Lexicographic (d, idx) xor min-reduce over the 8 groups of the half.
#pragma unroll
  for (int off = 4; off <= 16; off <<= 1) {
    float dg = __shfl_xor(d, off, 64);
    int ig = __shfl_xor(myc, off, 64);
    if (dg < d || (dg == d && ig < myc)) { d = dg; myc = ig; }
  }
  // all 32 lanes of the half now hold bidx in myc.

  const float4* cbest = reinterpret_cast<const float4*>(cb + (size_t)myc * C_DIM);
  float4 cl = cbest[sl];
  float4 zl = zr[sl];
  reinterpret_cast<float4*>(zq + (size_t)row * C_DIM)[sl] = cl;

  double dx = (double)zl.x - (double)cl.x;
  double dy = (double)zl.y - (double)cl.y;
  double dz = (double)zl.z - (double)cl.z;
  double dw = (double)zl.w - (double)cl.w;
  double l = (dx * dx + dy * dy) + (dz * dz + dw * dw);
#pragma unroll
  for (int off = 1; off <= 32; off <<= 1) l += __shfl_xor(l, off, 64);
  // stride-32 crossed halves: l = row0 + row1 combined (block partial needs
  // only the total).

  if (sl == 0) idx_f[row] = (float)myc;
  __shared__ double sh[4];
  if (lane == 0) sh[w] = l;
  __syncthreads();
  if (threadIdx.x == 0)
    partial[blockIdx.x] = (sh[0] + sh[1]) + (sh[2] + sh[3]);
}

__global__ __launch_bounds__(256) void finalize_kernel(
    const double* __restrict__ partial, float* __restrict__ out_loss) {
  double s = 0.0;
  for (int i = threadIdx.x; i < NBLK_R; i += 256) s += partial[i];
#pragma unroll
  for (int off = 32; off >= 1; off >>= 1) s += __shfl_down(s, off, 64);
  __shared__ double sh[4];
  int wv = threadIdx.x >> 6, lane = threadIdx.x & 63;
  if (lane == 0) sh[wv] = s;
  __syncthreads();
  if (threadIdx.x == 0) {
    double tot = sh[0] + sh[1] + sh[2] + sh[3];
    double mse = tot / (double)((size_t)N_TOT * C_DIM);
    *out_loss = (float)(1.75 * mse);  // 0.75*q_latent + e_latent, both == mse
  }
}

// ---------------------------------------------------------------------------
extern "C" void kernel_launch(void* const* d_in, const int* in_sizes, int n_in,
                              void* d_out, int out_size, void* d_ws, size_t ws_size,
                              hipStream_t stream) {
  const float* ze = (const float*)d_in[0];
  const float* cb = (const float*)d_in[1];

  float* out = (float*)d_out;
  float* zq = out;                                   // [N*C]
  float* out_loss = out + (size_t)N_TOT * C_DIM;     // [1]
  float* idx_f = out_loss + 1;                       // [N]

  float* cbsq = (float*)d_ws;                             // 4 KB @0
  ushort* cbh = (ushort*)((char*)d_ws + 8192);            // 256 KB
  ushort* cand = (ushort*)((char*)d_ws + 270336);         // 1 MB
  double* partial = (double*)((char*)d_ws + 1318912);     // 64 KB

  prep_kernel<<<K_CB / 4, 256, 0, stream>>>(cb, cbsq, cbh);
  dist_mfma_kernel<<<N_TOT / BN, 256, 0, stream>>>(ze, cbh, cbsq, cand);
  rescore_kernel<<<NBLK_R, 256, 0, stream>>>(ze, cb, cbsq, cand, zq, idx_f, partial);
  finalize_kernel<<<1, 256, 0, stream>>>(partial, out_loss);
}

// Round 7
// 135.162 us; speedup vs baseline: 4.1268x; 1.1197x over previous
//
#include <hip/hip_runtime.h>

#define N_TOT 65536
#define C_DIM 128
#define K_CB  1024
#define BN 64
#define BT 64
#define NTILE (K_CB / BT)
#define NBLK_D (N_TOT / BN)            // 1024 fused blocks

typedef __attribute__((ext_vector_type(8))) short bf16x8;   // 8 bf16 = 4 VGPR
typedef __attribute__((ext_vector_type(4))) float f32x4;

__device__ __forceinline__ ushort f2bf_rne(float f) {
  unsigned u = __float_as_uint(f);
  return (ushort)((u + 0x7FFFu + ((u >> 16) & 1u)) >> 16);
}

// med3u: inserting pk into sorted (t0<=t1<=t2) -> {min, med3, med3}: 3 VALU.
__device__ __forceinline__ unsigned med3u(unsigned a, unsigned b, unsigned c) {
  unsigned d;
  asm("v_med3_u32 %0, %1, %2, %3" : "=v"(d) : "v"(a), "v"(b), "v"(c));
  return d;
}

#define GLDS16(src, dst)                                                       \
  __builtin_amdgcn_global_load_lds(                                            \
      (const __attribute__((address_space(1))) void*)(src),                    \
      (__attribute__((address_space(3))) void*)(dst), 16, 0, 0)

// ---------------------------------------------------------------------------
// prep = cbsq (fp64 row sumsq, frozen math) + cbconv (bf16 RNE, same layout).
// NO global atomics (R3 lesson: 16384-way contended fp64 CAS = +400 µs).
// ---------------------------------------------------------------------------
__global__ __launch_bounds__(256) void prep_kernel(
    const float* __restrict__ cb, float* __restrict__ cbsq,
    ushort* __restrict__ cbh) {
  int w = threadIdx.x >> 6, lane = threadIdx.x & 63;
  int r = blockIdx.x * 4 + w;
  float2 v = reinterpret_cast<const float2*>(cb + (size_t)r * C_DIM)[lane];
  ushort2 h;
  h.x = f2bf_rne(v.x); h.y = f2bf_rne(v.y);
  reinterpret_cast<ushort2*>(cbh + (size_t)r * C_DIM)[lane] = h;
  double s = (double)v.x * (double)v.x + (double)v.y * (double)v.y;
#pragma unroll
  for (int off = 32; off >= 1; off >>= 1) s += __shfl_xor(s, off, 64);
  if (lane == 0) cbsq[r] = (float)s;
}

// ---------------------------------------------------------------------------
// FUSED dist+rescore (R7):
//  - dist section = R5 structure verbatim (cross-tile sort defer, LDS 36864,
//    source-side XOR swizzle, med3 insert) — validated R5/R6.
//  - top-8 per row now lands in LDS candS (1 KB) instead of global: cand
//    buffer + 1 MB round-trip + one kernel launch removed.
//  - rescore section = R6's verified half-wave scheme looped 8x over the
//    block's 64 rows. fp32 rounding points preserved exactly:
//    zs=fl32(fp64 sum), tt=fl32(2*p64), u=zs-tt, d=u+cbsq32, tie->low idx.
//  - Why fuse: R5/R6 counters show both kernels leave all pipes <40% busy;
//    fused, blocks in the fp64/L2-gather phase co-schedule with blocks in
//    the MFMA/LDS phase (disjoint pipes) instead of running serially.
// ---------------------------------------------------------------------------
__global__ __launch_bounds__(256, 4) void dist_rescore_kernel(
    const float* __restrict__ ze, const ushort* __restrict__ cbh,
    const float* __restrict__ cbsq, const float* __restrict__ cb,
    float* __restrict__ zq, float* __restrict__ idx_f,
    double* __restrict__ partial) {
  // [B0 16K | B1 16K (zh aliases) | cbsq 4K]; pool[24832] aliases B0+B1 head;
  // candS @30720 (1K, above pool); loss partials @32768 (cbsqS dead by then).
  __shared__ __align__(16) char smem[36864];
  char* const B0 = smem;
  char* const B1 = smem + 16384;
  ushort* zhS = reinterpret_cast<ushort*>(B1);            // [64][128] xor-swz
  unsigned* pool = reinterpret_cast<unsigned*>(smem);     // [64][97]
  float* const cbsqS = reinterpret_cast<float*>(smem + 32768);
  ushort* const candS = reinterpret_cast<ushort*>(smem + 30720);  // [64][8]
  double* const shl = reinterpret_cast<double*>(smem + 32768);    // [4]

  const int tid = threadIdx.x;
  const int w = tid >> 6, lane = tid & 63;
  const int mh = w & 1, nh = w >> 1;
  const int c16 = lane & 15, quad = lane >> 4;
  const int rowbase = blockIdx.x * BN;

  // Per-lane pre-swizzled source offsets for B staging (t-independent).
  int soff[4];
#pragma unroll
  for (int i = 0; i < 4; ++i) {
    int o = w * 4096 + i * 1024 + lane * 16;
    int row = o >> 8, inrow = o & 255;
    soff[i] = row * 256 + (inrow ^ ((row & 7) << 4));
  }
  const int stoff = w * 4096;   // wave-uniform LDS base within buffer

  // Tile-0 B stage into B0 (in flight across z staging; disjoint from zhS=B1).
#pragma unroll
  for (int i = 0; i < 4; ++i)
    GLDS16((const char*)cbh + soff[i], B0 + stoff + i * 1024);

  // Stage z tile -> bf16 LDS (one time), into B1 region.
#pragma unroll
  for (int p = 0; p < 4; ++p) {
    int fid = p * 256 + tid;
    int row = fid >> 4, c8 = fid & 15;
    float4 a = reinterpret_cast<const float4*>(ze)[(size_t)(rowbase + row) * 32 + c8 * 2];
    float4 b = reinterpret_cast<const float4*>(ze)[(size_t)(rowbase + row) * 32 + c8 * 2 + 1];
    ushort h[8] = {f2bf_rne(a.x), f2bf_rne(a.y), f2bf_rne(a.z), f2bf_rne(a.w),
                   f2bf_rne(b.x), f2bf_rne(b.y), f2bf_rne(b.z), f2bf_rne(b.w)};
    *reinterpret_cast<uint4*>(&zhS[row * 128 + ((c8 ^ (row & 7)) * 8)]) =
        *reinterpret_cast<const uint4*>(h);
  }
  // cbsq -> LDS (1024 floats).
  reinterpret_cast<float4*>(cbsqS)[tid] = reinterpret_cast<const float4*>(cbsq)[tid];
  __syncthreads();   // #1: tile-0 B stage + z writes + cbsq all visible

  // Hoist A-frags from zhS(=B1): afrag[m2][ks].
  const int xk = c16 & 7;
  bf16x8 afrag[2][4];
#pragma unroll
  for (int m2 = 0; m2 < 2; ++m2) {
    int r = (mh * 32 + m2 * 16 + c16) * 128;
#pragma unroll
    for (int ks = 0; ks < 4; ++ks)
      afrag[m2][ks] = *reinterpret_cast<const bf16x8*>(&zhS[r + ((ks * 4 + quad) ^ xk) * 8]);
  }
  __syncthreads();   // #2: zhS dead -> B1 stageable

  unsigned t3[8][3];
#pragma unroll
  for (int s = 0; s < 8; ++s) { t3[s][0] = 0xFFFFFFFFu; t3[s][1] = 0xFFFFFFFFu; t3[s][2] = 0xFFFFFFFFu; }

  const int cbase = nh * 32 + c16;

  auto STAGE = [&](int t, char* dst) {
#pragma unroll
    for (int i = 0; i < 4; ++i)
      GLDS16((const char*)cbh + (size_t)t * 16384 + soff[i], dst + stoff + i * 1024);
  };
  auto READ_MFMA = [&](const char* buf, f32x4 (&acc)[2][2]) {
    bf16x8 bf[2][4];
#pragma unroll
    for (int n2 = 0; n2 < 2; ++n2) {
      int rb = (nh * 32 + n2 * 16 + c16) * 256;
#pragma unroll
      for (int ks = 0; ks < 4; ++ks)
        bf[n2][ks] = *reinterpret_cast<const bf16x8*>(buf + rb + (((ks * 4 + quad) ^ xk) << 4));
    }
#pragma unroll
    for (int m2 = 0; m2 < 2; ++m2)
#pragma unroll
      for (int n2 = 0; n2 < 2; ++n2) acc[m2][n2] = (f32x4){0.f, 0.f, 0.f, 0.f};
#pragma unroll
    for (int ks = 0; ks < 4; ++ks)
#pragma unroll
      for (int m2 = 0; m2 < 2; ++m2)
#pragma unroll
        for (int n2 = 0; n2 < 2; ++n2)
          acc[m2][n2] = __builtin_amdgcn_mfma_f32_16x16x32_bf16(afrag[m2][ks], bf[n2][ks], acc[m2][n2], 0, 0, 0);
  };
  auto SORT = [&](const f32x4 (&acc)[2][2], int t) {
#pragma unroll
    for (int n2 = 0; n2 < 2; ++n2) {
      int code = t * BT + cbase + n2 * 16;
      unsigned codeu = (unsigned)code & 1023u;
      float csb = cbsqS[code] + 192.0f;
#pragma unroll
      for (int m2 = 0; m2 < 2; ++m2)
#pragma unroll
        for (int reg = 0; reg < 4; ++reg) {
          float kf = fmaf(-2.f, acc[m2][n2][reg], csb);
          unsigned pk = (__float_as_uint(kf) & 0xFFFFFC00u) | codeu;
          int s = m2 * 4 + reg;
          unsigned n0 = min(t3[s][0], pk);
          unsigned n1 = med3u(t3[s][0], t3[s][1], pk);
          unsigned n2v = med3u(t3[s][1], t3[s][2], pk);
          t3[s][0] = n0; t3[s][1] = n1; t3[s][2] = n2v;
        }
    }
  };

  f32x4 accA[2][2], accB[2][2];

  // tile 0 (B0 staged+drained at #1); stage tile 1 into B1.
  STAGE(1, B1);
  READ_MFMA(B0, accA);
  __syncthreads();   // #3: stage(1) drained; all B0 reads done

  for (int tp = 0; tp < 7; ++tp) {
    int t = 2 * tp + 1;                 // odd tile, lives in B1
    STAGE(t + 1, B0);                   // even tile -> B0
    SORT(accA, t - 1);                  // sort even tile t-1 (overlaps reads)
    READ_MFMA(B1, accB);                // tile t
    __syncthreads();
    STAGE(t + 2, B1);                   // odd tile -> B1
    SORT(accB, t);
    READ_MFMA(B0, accA);                // tile t+1
    __syncthreads();
  }
  // tiles 14 (accA, unsorted) and 15 (staged in B1, drained).
  SORT(accA, 14);
  READ_MFMA(B1, accB);
  SORT(accB, 15);
  __syncthreads();   // all waves done reading B0/B1 before pool overwrite

  // Pool: 32 (nh,c16) groups x top-3 = 96 packed keys per row.
#pragma unroll
  for (int s = 0; s < 8; ++s) {
    int row = mh * 32 + (s >> 2) * 16 + quad * 4 + (s & 3);
    int col = (nh * 16 + c16) * 3;
    pool[row * 97 + col] = t3[s][0];
    pool[row * 97 + col + 1] = t3[s][1];
    pool[row * 97 + col + 2] = t3[s][2];
  }
  __syncthreads();
  if (tid < BN) {
    unsigned k[8];
#pragma unroll
    for (int q = 0; q < 8; ++q) k[q] = 0xFFFFFFFFu;
    for (int p = 0; p < 96; ++p) {
      unsigned v = pool[tid * 97 + p];
      if (v < k[7]) {
        k[7] = v;
#pragma unroll
        for (int q = 7; q > 0; --q)
          if (k[q] < k[q - 1]) { unsigned tk = k[q]; k[q] = k[q - 1]; k[q - 1] = tk; }
      }
    }
    uint4 cw;
    cw.x = (k[0] & 1023u) | ((k[1] & 1023u) << 16);
    cw.y = (k[2] & 1023u) | ((k[3] & 1023u) << 16);
    cw.z = (k[4] & 1023u) | ((k[5] & 1023u) << 16);
    cw.w = (k[6] & 1023u) | ((k[7] & 1023u) << 16);
    reinterpret_cast<uint4*>(candS)[tid] = cw;   // LDS, not global
  }
  __syncthreads();   // candS visible to all waves

  // ---- rescore phase (R6 half-wave scheme, 8 iters x 8 rows) ----
  const int h2 = lane >> 5, sl = lane & 31;
  const int g = sl >> 2, e = sl & 3;
  double lacc = 0.0;
#pragma unroll 1
  for (int it = 0; it < 8; ++it) {
    int rl = it * 8 + w * 2 + h2;
    int row = rowbase + rl;
    int myc = candS[rl * 8 + g];

    const float4* zr = reinterpret_cast<const float4*>(ze + (size_t)row * C_DIM);
    const float4* cr = reinterpret_cast<const float4*>(cb + (size_t)myc * C_DIM);

    double p0 = 0.0, p1 = 0.0, zs0 = 0.0, zs1 = 0.0;
#pragma unroll
    for (int j = 0; j < 8; ++j) {
      float4 zf = zr[e + 4 * j];
      float4 cf = cr[e + 4 * j];
      double a = ((double)zf.x * (double)cf.x + (double)zf.y * (double)cf.y) +
                 ((double)zf.z * (double)cf.z + (double)zf.w * (double)cf.w);
      double b = ((double)zf.x * (double)zf.x + (double)zf.y * (double)zf.y) +
                 ((double)zf.z * (double)zf.z + (double)zf.w * (double)zf.w);
      if (j & 1) { p1 += a; zs1 += b; } else { p0 += a; zs0 += b; }
    }
    double pp = p0 + p1;
    double zsum = zs0 + zs1;
    pp += __shfl_xor(pp, 1, 64);
    pp += __shfl_xor(pp, 2, 64);
    zsum += __shfl_xor(zsum, 1, 64);
    zsum += __shfl_xor(zsum, 2, 64);

    float zs = (float)zsum;
    float tt = (float)(2.0 * pp);
    float u = zs - tt;
    float d = u + cbsq[myc];

    // Lexicographic (d, idx) xor min-reduce over the 8 groups of the half.
#pragma unroll
    for (int off = 4; off <= 16; off <<= 1) {
      float dg = __shfl_xor(d, off, 64);
      int ig = __shfl_xor(myc, off, 64);
      if (dg < d || (dg == d && ig < myc)) { d = dg; myc = ig; }
    }

    const float4* cbest = reinterpret_cast<const float4*>(cb + (size_t)myc * C_DIM);
    float4 cl = cbest[sl];
    float4 zl = zr[sl];
    reinterpret_cast<float4*>(zq + (size_t)row * C_DIM)[sl] = cl;

    double dx = (double)zl.x - (double)cl.x;
    double dy = (double)zl.y - (double)cl.y;
    double dz = (double)zl.z - (double)cl.z;
    double dw = (double)zl.w - (double)cl.w;
    double l = (dx * dx + dy * dy) + (dz * dz + dw * dw);
#pragma unroll
    for (int off = 1; off <= 32; off <<= 1) l += __shfl_xor(l, off, 64);
    lacc += l;   // rows rl(h2=0)+rl(h2=1) combined (stride-32 crossing)

    if (sl == 0) idx_f[row] = (float)myc;
  }

  if (lane == 0) shl[w] = lacc;
  __syncthreads();
  if (tid == 0)
    partial[blockIdx.x] = (shl[0] + shl[1]) + (shl[2] + shl[3]);
}

__global__ __launch_bounds__(256) void finalize_kernel(
    const double* __restrict__ partial, float* __restrict__ out_loss) {
  double s = 0.0;
  for (int i = threadIdx.x; i < NBLK_D; i += 256) s += partial[i];
#pragma unroll
  for (int off = 32; off >= 1; off >>= 1) s += __shfl_down(s, off, 64);
  __shared__ double sh[4];
  int wv = threadIdx.x >> 6, lane = threadIdx.x & 63;
  if (lane == 0) sh[wv] = s;
  __syncthreads();
  if (threadIdx.x == 0) {
    double tot = sh[0] + sh[1] + sh[2] + sh[3];
    double mse = tot / (double)((size_t)N_TOT * C_DIM);
    *out_loss = (float)(1.75 * mse);  // 0.75*q_latent + e_latent, both == mse
  }
}

// ---------------------------------------------------------------------------
extern "C" void kernel_launch(void* const* d_in, const int* in_sizes, int n_in,
                              void* d_out, int out_size, void* d_ws, size_t ws_size,
                              hipStream_t stream) {
  const float* ze = (const float*)d_in[0];
  const float* cb = (const float*)d_in[1];

  float* out = (float*)d_out;
  float* zq = out;                                   // [N*C]
  float* out_loss = out + (size_t)N_TOT * C_DIM;     // [1]
  float* idx_f = out_loss + 1;                       // [N]

  float* cbsq = (float*)d_ws;                             // 4 KB @0
  ushort* cbh = (ushort*)((char*)d_ws + 8192);            // 256 KB
  double* partial = (double*)((char*)d_ws + 270336);      // 8 KB

  prep_kernel<<<K_CB / 4, 256, 0, stream>>>(cb, cbsq, cbh);
  dist_rescore_kernel<<<NBLK_D, 256, 0, stream>>>(ze, cbh, cbsq, cb, zq,
                                                  idx_f, partial);
  finalize_kernel<<<1, 256, 0, stream>>>(partial, out_loss);
}